// Round 5
// baseline (294.861 us; speedup 1.0000x reference)
//
#include <hip/hip_runtime.h>

#define NQ 18
#define BATCH 64

// ---------------------------------------------------------------------------
// Real-state simulator. d_out = 16,777,216 f32 = Re(state), (64, 2^18).
// The RX encoding makes amp = (real product) * (-i)^popcount; RY layers and
// CNOT ladders are real -> Re(state) evolves closed under the whole circuit.
//
// Qubit q <-> amp bit (17-q) (wire 0 most significant).
// CNOT ladder (q=0..16) as an index map: final[out] = pre[in], in = out ^ (out>>1).
// Factorized over 6-bit groups G0 = bits 17..12, G1 = 11..6, G2 = 5..0:
//   stored G0' = px6(G0); G1' = px6(G1) ^ 0x3F*par(G0); G2' = px6(G2) ^ 0x3F*par(G0^G1)
// where px6 = prefix-xor from MSB, inv px6(y) = y ^ (y>>1).
// ---------------------------------------------------------------------------

__device__ __forceinline__ float2 cmul(float2 a, float2 b) {
    return make_float2(a.x * b.x - a.y * b.y, a.x * b.y + a.y * b.x);
}

// k_init: full layer 0 (RX encode + RY layer-0 + ladder), write Re only.
// Thread owns a 32-f32 contiguous OUT window. 2^19 threads.
// in bits 17..5 = OW ^ (OW>>1); in bits 4..0 = inv_px5(oj) ^ (OW_0 ? 16 : 0).
__global__ __launch_bounds__(256) void k_init(const float* __restrict__ inputs,
                                              const float* __restrict__ params,
                                              float* __restrict__ S) {
    __shared__ float2 vt[2][NQ];                // v[q] = RY(p0q/2)*RX(x/2)|0>
    int g = blockIdx.x * 256 + threadIdx.x;     // [0, 2^19)
    int b = g >> 13;                            // 32 blocks per sample: b block-uniform
    int t = threadIdx.x;
    if (t < NQ) {
        float x  = 0.5f * inputs[b * NQ + t];
        float cx = cosf(x), sx = sinf(x);
        float th = 0.5f * params[t];            // layer 0
        float c  = cosf(th), s = sinf(th);
        vt[0][t] = make_float2(c * cx,  s * sx);    // c*cx + i*s*sx
        vt[1][t] = make_float2(s * cx, -c * sx);    // s*cx - i*c*sx
    }
    __syncthreads();

    unsigned OW = (unsigned)(g & 0x1FFF);       // out bits 17..5 (within sample)
    unsigned iu = OW ^ (OW >> 1);               // in bits 17..5
    int pu = OW & 1;                            // out bit 5 -> flips in bit 4

    float2 p = make_float2(1.f, 0.f);           // product over qubits 0..12
    #pragma unroll
    for (int q = 0; q <= 12; ++q) {             // qubit q <-> iu bit (12-q)
        int bit = (iu >> (12 - q)) & 1;
        p = cmul(p, vt[bit][q]);
    }

    float2 a[32];                               // doubling qubits 13..17; a-bit bp <-> qubit 17-bp
    a[0] = p;
    #pragma unroll
    for (int bp = 0; bp < 5; ++bp) {
        float2 v0 = vt[0][17 - bp], v1 = vt[1][17 - bp];
        if (bp == 4 && pu) { float2 tt = v0; v0 = v1; v1 = tt; }   // fold ^16
        #pragma unroll
        for (int i = (1 << bp) - 1; i >= 0; --i) {
            float2 base = a[i];
            a[i + (1 << bp)] = cmul(base, v1);
            a[i] = cmul(base, v0);
        }
    }

    float* out = S + ((size_t)b << NQ) + ((size_t)OW << 5);
    #pragma unroll
    for (int oj = 0; oj < 32; oj += 4) {        // slot oj <- a[inv_px5(oj)]
        int k0 = oj ^ (oj >> 1);                // oj%4==0 -> partners k0^1, k0^3, k0^2
        *(float4*)(out + oj) = make_float4(a[k0].x, a[k0 ^ 1].x, a[k0 ^ 3].x, a[k0 ^ 2].x);
    }
}

// k_pass<P>: shared-angle RY on qubits 6P..6P+5 + that group's ladder slice
// folded into the write permutation. Thread owns a 64-f32 orbit (group bits
// free, all else fixed): in-place, race-free. hm = accumulated ladder parity
// from higher groups (recovered from stored permuted bits).
template<int P>
__global__ __launch_bounds__(256) void k_pass(const float* __restrict__ params,
                                              float* __restrict__ S, int layer) {
    int g = blockIdx.x * 256 + threadIdx.x;     // [0, 2^18)
    float cg[6], sg[6];
    #pragma unroll
    for (int i = 0; i < 6; ++i) {
        float th = 0.5f * params[layer * NQ + 6 * P + i];
        cg[i] = cosf(th); sg[i] = sinf(th);
    }
    size_t base; int hm;
    constexpr int STR = (P == 0) ? 4096 : (P == 1) ? 64 : 1;
    if constexpr (P == 0) {
        base = ((size_t)(g >> 12) << NQ) | (size_t)(g & 0xFFF);
        hm = 0;
    } else if constexpr (P == 1) {
        base = ((size_t)(g >> 12) << NQ) | ((size_t)((g >> 6) & 63) << 12) | (size_t)(g & 63);
        hm = (g >> 6) & 1;                      // stored amp bit 12 = par(G0)
    } else {
        base = (size_t)g << 6;
        hm = g & 1;                             // stored amp bit 6 = par(G0^G1)
    }

    float a[64];
    if constexpr (P == 2) {
        #pragma unroll
        for (int j = 0; j < 64; j += 4) {
            float4 w = *(const float4*)(S + base + j);
            a[j] = w.x; a[j + 1] = w.y; a[j + 2] = w.z; a[j + 3] = w.w;
        }
    } else {
        #pragma unroll
        for (int j = 0; j < 64; ++j) a[j] = S[base + (size_t)j * STR];
    }

    #pragma unroll
    for (int i = 0; i < 6; ++i) {               // qubit 6P+i <-> j bit (5-i)
        int m = 32 >> i;
        #pragma unroll
        for (int r = 0; r < 64; ++r) if (!(r & m)) {
            float x0 = a[r], x1 = a[r | m];
            a[r]     = cg[i] * x0 - sg[i] * x1;
            a[r | m] = sg[i] * x0 + cg[i] * x1;
        }
    }
    if (hm) {                                   // fold ^0x3F on out slot = ^0x20 on a-index
        #pragma unroll
        for (int r = 0; r < 32; ++r) { float tt = a[r]; a[r] = a[r ^ 32]; a[r ^ 32] = tt; }
    }
    if constexpr (P == 2) {
        #pragma unroll
        for (int oj = 0; oj < 64; oj += 4) {    // slot oj <- a[inv_px6(oj)]
            int k0 = oj ^ (oj >> 1);
            *(float4*)(S + base + oj) =
                make_float4(a[k0], a[k0 ^ 1], a[k0 ^ 3], a[k0 ^ 2]);
        }
    } else {
        #pragma unroll
        for (int oj = 0; oj < 64; ++oj)
            S[base + (size_t)oj * STR] = a[oj ^ (oj >> 1)];
    }
}

extern "C" void kernel_launch(void* const* d_in, const int* in_sizes, int n_in,
                              void* d_out, int out_size, void* d_ws, size_t ws_size,
                              hipStream_t stream) {
    const float* inputs = (const float*)d_in[0];   // (64, 18) f32
    const float* params = (const float*)d_in[1];   // (4, 18, 1) f32
    float* S = (float*)d_out;                      // (64, 2^18) f32 = Re(state), in-place

    k_init<<<2048, 256, 0, stream>>>(inputs, params, S);      // = full layer 0
    for (int layer = 1; layer < 4; ++layer) {
        k_pass<0><<<1024, 256, 0, stream>>>(params, S, layer);
        k_pass<1><<<1024, 256, 0, stream>>>(params, S, layer);
        k_pass<2><<<1024, 256, 0, stream>>>(params, S, layer);
    }
}

// Round 6
// 138.862 us; speedup vs baseline: 2.1234x; 2.1234x over previous
//
#include <hip/hip_runtime.h>
#include <utility>

#define NQ 18
#define BATCH 64

// ws float-offsets for the fast path
#define VT_OFFC (1u << 24)                      // 64*2^18 state floats first
#define CS_OFFC (VT_OFFC + BATCH * NQ * 4)      // then vt table, then cos/sin table

__device__ __forceinline__ float2 cmulf(float2 a, float2 b) {
    return make_float2(a.x * b.x - a.y * b.y, a.x * b.y + a.y * b.x);
}

template<class F, int... Is>
__device__ __forceinline__ void unroll_impl(F f, std::integer_sequence<int, Is...>) {
    (f(std::integral_constant<int, Is>{}), ...);
}
template<int N, class F>
__device__ __forceinline__ void unroll(F f) {
    unroll_impl(f, std::make_integer_sequence<int, N>{});
}

// ---------------------------------------------------------------------------
// Gate algebra (storage order fixed = logical order at layer 1):
//  ladder = linear map T: s -> s ^ (s>>1)  (final[s] = pre[T s], verified R5)
//  layer-k RY(qubit q), p = 17-q, conjugated to stored coords:
//    mask m = T^(k-1) e_p ; orientation O = row p of T^-(k-1):
//      k=2: O = {p..17}; k=3: O = {p,p+2,p+4,..}; k=4: O = 0x33333 << p
//  flip(pair rep r, r&(1<<p)==0) = parity(x & O)  ->  use s_eff = -s.
//  Output perm: out[s] = A[T^4 s]  ->  write x to s = x^(x>>4)^(x>>8)^(x>>12)^(x>>16).
// ---------------------------------------------------------------------------
struct Gate { int k, p; };
constexpr Gate GT[54] = {
    // pass A phase 0, window x 12..17
    {2,13},{2,14},{2,15},{2,16},{2,17}, {3,14},{3,15},{3,16},{3,17}, {4,15},{4,16},{4,17},
    // phase 1, window x 10..15
    {2,11},{2,12}, {3,12},{3,13}, {4,13},{4,14},
    // phase 2, window x 7..12
    {2,8},{2,9},{2,10}, {3,9},{3,10},{3,11}, {4,10},{4,11},{4,12},
    // phase 3, window x 4..9
    {2,5},{2,6},{2,7}, {3,6},{3,7},{3,8}, {4,7},{4,8},{4,9},
    // pass B, window x 0..6
    {2,0},{2,1},{2,2},{2,3},{2,4},
    {3,0},{3,1},{3,2},{3,3},{3,4},{3,5},
    {4,0},{4,1},{4,2},{4,3},{4,4},{4,5},{4,6},
};
constexpr unsigned gmask(Gate g) {
    return g.k == 2 ? (g.p >= 1 ? 3u << (g.p - 1) : 1u)
         : g.k == 3 ? (g.p >= 2 ? 5u << (g.p - 2) : 1u << g.p)
         : (g.p >= 3 ? 15u << (g.p - 3) : (1u << (g.p + 1)) - 1u);
}
constexpr unsigned gorient(Gate g) {
    return g.k == 2 ? (0x3FFFFu & ~((1u << g.p) - 1u))
         : g.k == 3 ? ((0x15555u << g.p) & 0x3FFFFu)
         : ((0x33333u << g.p) & 0x3FFFFu);
}
constexpr int gcsi(Gate g) { return (g.k - 2) * NQ + (17 - g.p); }

// Apply NG gates (GT[OFF..OFF+NG)) on NR=2^w register window starting at x-bit WL.
// xfix = thread's x with window bits zeroed. All register indices compile-time.
template<int WL, int OFF, int NG, int NR>
__device__ __forceinline__ void apply_gates(float* a, unsigned xfix, const float* csn) {
    unroll<NG>([&](auto I) {
        constexpr Gate g = GT[OFF + I.value];
        constexpr unsigned m  = gmask(g);
        constexpr unsigned O  = gorient(g);
        constexpr unsigned mr = (m >> WL) & (unsigned)(NR - 1);
        constexpr unsigned hb = 1u << (g.p - WL);
        constexpr unsigned Or = (O >> WL) & (unsigned)(NR - 1);
        constexpr unsigned Of = O & ~(((unsigned)(NR - 1)) << WL);
        float c = csn[2 * gcsi(g)], s = csn[2 * gcsi(g) + 1];
        float ps = (__popc(xfix & Of) & 1) ? -s : s;
        float ms = -ps;
        unroll<NR>([&](auto R) {
            constexpr int r = R.value;
            if constexpr ((r & (int)hb) == 0) {
                constexpr int r2 = r ^ (int)mr;
                constexpr bool fl = (__builtin_popcount((unsigned)r & Or) & 1) != 0;
                float se = fl ? ms : ps;
                float x0 = a[r], x1 = a[r2];
                a[r]  = c * x0 - se * x1;
                a[r2] = se * x0 + c * x1;
            }
        });
    });
}

// prep: vt[b][q] = RY(p0q/2)*RX(x/2)|0> (4 floats), plus cos/sin for layers 1..3
__global__ void k_prep(const float* __restrict__ inputs, const float* __restrict__ params,
                       float* __restrict__ ws) {
    int t = blockIdx.x * blockDim.x + threadIdx.x;
    if (t < BATCH * NQ) {
        int q = t % NQ;
        float x = 0.5f * inputs[t];
        float cx = cosf(x), sx = sinf(x);
        float th = 0.5f * params[q];
        float c = cosf(th), s = sinf(th);
        float* v = ws + VT_OFFC + t * 4;
        v[0] = c * cx;  v[1] = s * sx;     // v0 = c*cx + i*s*sx
        v[2] = s * cx;  v[3] = -c * sx;    // v1 = s*cx - i*c*sx
    } else if (t < BATCH * NQ + 54) {
        int i = t - BATCH * NQ;            // (k-2)*18 + q  -> params[(k-1)*18+q]
        float th = 0.5f * params[NQ + i];
        ws[CS_OFFC + 2 * i]     = cosf(th);
        ws[CS_OFFC + 2 * i + 1] = sinf(th);
    }
}

// pass A: init product (layer 0 folded) + 36 gates on x bits 4..17.
// WG = (b, c4 = x bits 0..3); tile = 2^14 f32 in LDS; ws stored rotated:
// y = (x>>4) | ((x&15)<<14); WG writes contiguous [b<<18 | c4<<14, +2^14).
__global__ __launch_bounds__(256) void k_passA(const float* __restrict__ ws_tab,
                                               float* __restrict__ ws) {
    __shared__ float lds[16384];           // exactly 64 KiB
    const int b  = blockIdx.x >> 4;
    const int c4 = blockIdx.x & 15;
    const int t  = threadIdx.x;
    const float* vt  = ws_tab + VT_OFFC + b * NQ * 4;
    const float* csn = ws_tab + CS_OFFC;
    auto slot = [](unsigned y) { return y ^ ((y >> 6) & 31u); };  // <=2-way all phases

    // init: complex product, reg bit bp <-> x bit 12+bp <-> qubit 5-bp
    unsigned xf0 = (unsigned)c4 | ((unsigned)t << 4);   // x bits 0..11
    float2 pf = make_float2(1.f, 0.f);
    #pragma unroll
    for (int i = 0; i < 12; ++i) {
        int bit = (xf0 >> i) & 1;
        const float* vq = vt + (17 - i) * 4 + bit * 2;
        pf = cmulf(pf, make_float2(vq[0], vq[1]));
    }
    float2 ca[32];
    ca[0] = pf;
    #pragma unroll
    for (int bp = 0; bp < 5; ++bp) {
        const float* vq = vt + (5 - bp) * 4;
        float2 v0 = make_float2(vq[0], vq[1]), v1 = make_float2(vq[2], vq[3]);
        #pragma unroll
        for (int i = (1 << bp) - 1; i >= 0; --i) {
            float2 base = ca[i];
            ca[i + (1 << bp)] = cmulf(base, v1);
            ca[i] = cmulf(base, v0);
        }
    }
    float a[64];
    {
        const float* vq = vt;              // bp=5 <-> x bit 17 <-> qubit 0
        float2 v0 = make_float2(vq[0], vq[1]), v1 = make_float2(vq[2], vq[3]);
        #pragma unroll
        for (int i = 0; i < 32; ++i) {     // real part only from here on
            a[i]      = ca[i].x * v0.x - ca[i].y * v0.y;
            a[i + 32] = ca[i].x * v1.x - ca[i].y * v1.y;
        }
    }
    apply_gates<12, 0, 12, 64>(a, xf0, csn);

    // ph0 -> ph1
    #pragma unroll
    for (int j = 0; j < 64; ++j) lds[slot(((unsigned)j << 8) | (unsigned)t)] = a[j];
    __syncthreads();
    unsigned base1 = (unsigned)(t & 63) | ((unsigned)(t >> 6) << 12);
    #pragma unroll
    for (int j = 0; j < 64; ++j) a[j] = lds[slot(base1 | ((unsigned)j << 6))];
    unsigned xf1 = (unsigned)c4 | ((unsigned)(t & 63) << 4) | ((unsigned)(t >> 6) << 16);
    apply_gates<10, 12, 6, 64>(a, xf1, csn);
    #pragma unroll
    for (int j = 0; j < 64; ++j) lds[slot(base1 | ((unsigned)j << 6))] = a[j];
    __syncthreads();
    // ph2: t0..2 -> y0..2, t3..7 -> y9..13
    unsigned base2 = (unsigned)(t & 7) | ((unsigned)(t >> 3) << 9);
    #pragma unroll
    for (int j = 0; j < 64; ++j) a[j] = lds[slot(base2 | ((unsigned)j << 3))];
    unsigned xf2 = (unsigned)c4 | ((unsigned)(t & 7) << 4) | ((unsigned)(t >> 3) << 13);
    apply_gates<7, 18, 9, 64>(a, xf2, csn);
    #pragma unroll
    for (int j = 0; j < 64; ++j) lds[slot(base2 | ((unsigned)j << 3))] = a[j];
    __syncthreads();
    // ph3: y = j | t<<6
    #pragma unroll
    for (int j = 0; j < 64; ++j) a[j] = lds[slot((unsigned)j | ((unsigned)t << 6))];
    unsigned xf3 = (unsigned)c4 | ((unsigned)t << 10);
    apply_gates<4, 27, 9, 64>(a, xf3, csn);

    float4* w4 = (float4*)(ws + (((size_t)b << NQ) | ((size_t)c4 << 14) | ((size_t)t << 6)));
    #pragma unroll
    for (int j = 0; j < 64; j += 4)
        w4[j >> 2] = make_float4(a[j], a[j + 1], a[j + 2], a[j + 3]);
}

// pass B: 18 gates on x bits 0..6 (128 f32 in regs) + final T^-4 perm to d_out.
__global__ __launch_bounds__(256) void k_passB(const float* __restrict__ ws,
                                               float* __restrict__ out) {
    int tid = blockIdx.x * 256 + threadIdx.x;   // 131072 threads
    int b = tid >> 11;
    int o = tid & 2047;                          // x bits 7..17
    const float* csn = ws + CS_OFFC;
    unsigned xfix = (unsigned)o << 7;

    float a[128];                                // a[n], n = x bits 0..6
    const float4* g4 = (const float4*)(ws + ((size_t)b << NQ));
    #pragma unroll
    for (int h = 0; h < 16; ++h) {               // h = x bits 0..3 (y bits 14..17)
        unsigned yb = ((unsigned)h << 14) | ((unsigned)o << 3);
        float4 w0 = g4[yb >> 2];
        float4 w1 = g4[(yb >> 2) + 1];
        a[h]      = w0.x; a[h | 16] = w0.y; a[h | 32] = w0.z; a[h | 48] = w0.w;
        a[h | 64] = w1.x; a[h | 80] = w1.y; a[h | 96] = w1.z; a[h | 112] = w1.w;
    }
    apply_gates<0, 36, 18, 128>(a, xfix, csn);

    // out[s] = A[T^4 s]:  s = x ^ x>>4 ^ x>>8 ^ x>>12 ^ x>>16
    unsigned sall = xfix ^ (xfix >> 4) ^ (xfix >> 8) ^ (xfix >> 12) ^ (xfix >> 16);
    unsigned shiB = sall & ~127u;
    unsigned cc   = ((sall & 127u) ^ ((sall & 127u) >> 4)) & 127u;
    // relabel a'[r] = a[r ^ cc] (static-index swap network, 7 layers)
    unroll<7>([&](auto Bi) {
        constexpr int bit = 1 << Bi.value;
        bool dosw = ((cc >> Bi.value) & 1u) != 0;
        unroll<128>([&](auto R) {
            constexpr int r = R.value;
            if constexpr ((r & bit) == 0) {
                constexpr int r2 = r | bit;
                float t0 = a[r], t1 = a[r2];
                a[r]  = dosw ? t1 : t0;
                a[r2] = dosw ? t0 : t1;
            }
        });
    });
    float4* o4 = (float4*)(out + (((size_t)b << NQ) | shiB));
    unroll<32>([&](auto D) {                     // slot d <- a'[d ^ (d>>4)]
        constexpr int d0 = D.value << 2;
        constexpr int n0 = (d0 ^ (d0 >> 4)) & 127;
        o4[D.value] = make_float4(a[n0], a[n0 ^ 1], a[n0 ^ 2], a[n0 ^ 3]);
    });
}

// ======================= fallback (proven R5 path, no ws) =======================
__global__ __launch_bounds__(256) void k_init_f(const float* __restrict__ inputs,
                                                const float* __restrict__ params,
                                                float* __restrict__ S) {
    __shared__ float2 vt[2][NQ];
    int g = blockIdx.x * 256 + threadIdx.x;
    int b = g >> 13;
    int t = threadIdx.x;
    if (t < NQ) {
        float x = 0.5f * inputs[b * NQ + t];
        float cx = cosf(x), sx = sinf(x);
        float th = 0.5f * params[t];
        float c = cosf(th), s = sinf(th);
        vt[0][t] = make_float2(c * cx,  s * sx);
        vt[1][t] = make_float2(s * cx, -c * sx);
    }
    __syncthreads();
    unsigned OW = (unsigned)(g & 0x1FFF);
    unsigned iu = OW ^ (OW >> 1);
    int pu = OW & 1;
    float2 p = make_float2(1.f, 0.f);
    #pragma unroll
    for (int q = 0; q <= 12; ++q) {
        int bit = (iu >> (12 - q)) & 1;
        p = cmulf(p, vt[bit][q]);
    }
    float2 a[32];
    a[0] = p;
    #pragma unroll
    for (int bp = 0; bp < 5; ++bp) {
        float2 v0 = vt[0][17 - bp], v1 = vt[1][17 - bp];
        if (bp == 4 && pu) { float2 tt = v0; v0 = v1; v1 = tt; }
        #pragma unroll
        for (int i = (1 << bp) - 1; i >= 0; --i) {
            float2 base = a[i];
            a[i + (1 << bp)] = cmulf(base, v1);
            a[i] = cmulf(base, v0);
        }
    }
    float* outp = S + ((size_t)b << NQ) + ((size_t)OW << 5);
    #pragma unroll
    for (int oj = 0; oj < 32; oj += 4) {
        int k0 = oj ^ (oj >> 1);
        *(float4*)(outp + oj) = make_float4(a[k0].x, a[k0 ^ 1].x, a[k0 ^ 3].x, a[k0 ^ 2].x);
    }
}

template<int P>
__global__ __launch_bounds__(256) void k_pass_f(const float* __restrict__ params,
                                                float* __restrict__ S, int layer) {
    int g = blockIdx.x * 256 + threadIdx.x;
    float cg[6], sg[6];
    #pragma unroll
    for (int i = 0; i < 6; ++i) {
        float th = 0.5f * params[layer * NQ + 6 * P + i];
        cg[i] = cosf(th); sg[i] = sinf(th);
    }
    size_t base; int hm;
    constexpr int STR = (P == 0) ? 4096 : (P == 1) ? 64 : 1;
    if constexpr (P == 0) {
        base = ((size_t)(g >> 12) << NQ) | (size_t)(g & 0xFFF);
        hm = 0;
    } else if constexpr (P == 1) {
        base = ((size_t)(g >> 12) << NQ) | ((size_t)((g >> 6) & 63) << 12) | (size_t)(g & 63);
        hm = (g >> 6) & 1;
    } else {
        base = (size_t)g << 6;
        hm = g & 1;
    }
    float a[64];
    if constexpr (P == 2) {
        #pragma unroll
        for (int j = 0; j < 64; j += 4) {
            float4 w = *(const float4*)(S + base + j);
            a[j] = w.x; a[j + 1] = w.y; a[j + 2] = w.z; a[j + 3] = w.w;
        }
    } else {
        #pragma unroll
        for (int j = 0; j < 64; ++j) a[j] = S[base + (size_t)j * STR];
    }
    #pragma unroll
    for (int i = 0; i < 6; ++i) {
        int m = 32 >> i;
        #pragma unroll
        for (int r = 0; r < 64; ++r) if (!(r & m)) {
            float x0 = a[r], x1 = a[r | m];
            a[r]     = cg[i] * x0 - sg[i] * x1;
            a[r | m] = sg[i] * x0 + cg[i] * x1;
        }
    }
    if (hm) {
        #pragma unroll
        for (int r = 0; r < 32; ++r) { float tt = a[r]; a[r] = a[r ^ 32]; a[r ^ 32] = tt; }
    }
    if constexpr (P == 2) {
        #pragma unroll
        for (int oj = 0; oj < 64; oj += 4) {
            int k0 = oj ^ (oj >> 1);
            *(float4*)(S + base + oj) = make_float4(a[k0], a[k0 ^ 1], a[k0 ^ 3], a[k0 ^ 2]);
        }
    } else {
        #pragma unroll
        for (int oj = 0; oj < 64; ++oj)
            S[base + (size_t)oj * STR] = a[oj ^ (oj >> 1)];
    }
}

extern "C" void kernel_launch(void* const* d_in, const int* in_sizes, int n_in,
                              void* d_out, int out_size, void* d_ws, size_t ws_size,
                              hipStream_t stream) {
    const float* inputs = (const float*)d_in[0];   // (64, 18) f32
    const float* params = (const float*)d_in[1];   // (4, 18, 1) f32
    float* out = (float*)d_out;                    // (64, 2^18) f32 = Re(state)
    float* ws  = (float*)d_ws;
    const size_t need = (size_t)4 * ((1ull << 24) + BATCH * NQ * 4 + 108);

    if (ws_size >= need) {
        k_prep<<<5, 256, 0, stream>>>(inputs, params, ws);
        k_passA<<<BATCH * 16, 256, 0, stream>>>(ws, ws);
        k_passB<<<512, 256, 0, stream>>>(ws, out);
    } else {
        k_init_f<<<2048, 256, 0, stream>>>(inputs, params, out);
        for (int layer = 1; layer < 4; ++layer) {
            k_pass_f<0><<<1024, 256, 0, stream>>>(params, out, layer);
            k_pass_f<1><<<1024, 256, 0, stream>>>(params, out, layer);
            k_pass_f<2><<<1024, 256, 0, stream>>>(params, out, layer);
        }
    }
}

// Round 8
// 114.386 us; speedup vs baseline: 2.5778x; 1.2140x over previous
//
#include <hip/hip_runtime.h>
#include <utility>

#define NQ 18
#define BATCH 64

// ws float-offsets for the fast path
#define VT_OFFC (1u << 24)                      // 64*2^18 state floats first
#define CS_OFFC (VT_OFFC + BATCH * NQ * 4)      // then vt table, then cos/sin table

__device__ __forceinline__ float2 cmulf(float2 a, float2 b) {
    return make_float2(a.x * b.x - a.y * b.y, a.x * b.y + a.y * b.x);
}

template<class F, int... Is>
__device__ __forceinline__ void unroll_impl(F f, std::integer_sequence<int, Is...>) {
    (f(std::integral_constant<int, Is>{}), ...);
}
template<int N, class F>
__device__ __forceinline__ void unroll(F f) {
    unroll_impl(f, std::make_integer_sequence<int, N>{});
}

// ---------------------------------------------------------------------------
// Gate algebra (storage order fixed = logical order at layer 1):
//  ladder = linear map T: s -> s ^ (s>>1)  (final[s] = pre[T s])
//  layer-k RY(qubit q), p = 17-q, conjugated to stored coords:
//    mask m = T^(k-1) e_p ; orientation O = row p of T^-(k-1)
//  Output perm: out[s] = A[T^4 s], T^4 s = s ^ (s>>4).
// ---------------------------------------------------------------------------
struct Gate { int k, p; };
constexpr Gate GT[54] = {
    // pass A phase 0, window x 12..17
    {2,13},{2,14},{2,15},{2,16},{2,17}, {3,14},{3,15},{3,16},{3,17}, {4,15},{4,16},{4,17},
    // phase 1, window x 10..15
    {2,11},{2,12}, {3,12},{3,13}, {4,13},{4,14},
    // phase 2, window x 7..12
    {2,8},{2,9},{2,10}, {3,9},{3,10},{3,11}, {4,10},{4,11},{4,12},
    // phase 3, window x 4..9
    {2,5},{2,6},{2,7}, {3,6},{3,7},{3,8}, {4,7},{4,8},{4,9},
    // pass B, window x 0..6
    {2,0},{2,1},{2,2},{2,3},{2,4},
    {3,0},{3,1},{3,2},{3,3},{3,4},{3,5},
    {4,0},{4,1},{4,2},{4,3},{4,4},{4,5},{4,6},
};
constexpr unsigned gmask(Gate g) {
    return g.k == 2 ? (g.p >= 1 ? 3u << (g.p - 1) : 1u)
         : g.k == 3 ? (g.p >= 2 ? 5u << (g.p - 2) : 1u << g.p)
         : (g.p >= 3 ? 15u << (g.p - 3) : (1u << (g.p + 1)) - 1u);
}
constexpr unsigned gorient(Gate g) {
    return g.k == 2 ? (0x3FFFFu & ~((1u << g.p) - 1u))
         : g.k == 3 ? ((0x15555u << g.p) & 0x3FFFFu)
         : ((0x33333u << g.p) & 0x3FFFFu);
}
constexpr int gcsi(Gate g) { return (g.k - 2) * NQ + (17 - g.p); }

// Apply NG gates (GT[OFF..OFF+NG)) on NR=2^w register window starting at x-bit WL.
template<int WL, int OFF, int NG, int NR>
__device__ __forceinline__ void apply_gates(float* a, unsigned xfix, const float* csn) {
    unroll<NG>([&](auto I) {
        constexpr Gate g = GT[OFF + I.value];
        constexpr unsigned m  = gmask(g);
        constexpr unsigned O  = gorient(g);
        constexpr unsigned mr = (m >> WL) & (unsigned)(NR - 1);
        constexpr unsigned hb = 1u << (g.p - WL);
        constexpr unsigned Or = (O >> WL) & (unsigned)(NR - 1);
        constexpr unsigned Of = O & ~(((unsigned)(NR - 1)) << WL);
        float c = csn[2 * gcsi(g)], s = csn[2 * gcsi(g) + 1];
        float ps = (__popc(xfix & Of) & 1) ? -s : s;
        float ms = -ps;
        unroll<NR>([&](auto R) {
            constexpr int r = R.value;
            if constexpr ((r & (int)hb) == 0) {
                constexpr int r2 = r ^ (int)mr;
                constexpr bool fl = (__builtin_popcount((unsigned)r & Or) & 1) != 0;
                float se = fl ? ms : ps;
                float x0 = a[r], x1 = a[r2];
                a[r]  = c * x0 - se * x1;
                a[r2] = se * x0 + c * x1;
            }
        });
    });
}

// component unpermute by XOR k (k in 0..3): t_c <- r_{c^k}
__device__ __forceinline__ float4 perm4(float4 r, int k) {
    float t0 = r.x, t1 = r.y, t2 = r.z, t3 = r.w;
    if (k & 1) { float x; x=t0;t0=t1;t1=x; x=t2;t2=t3;t3=x; }
    if (k & 2) { float x; x=t0;t0=t2;t2=x; x=t1;t1=t3;t3=x; }
    return make_float4(t0, t1, t2, t3);
}

// prep: vt[b][q] = RY(p0q/2)*RX(x/2)|0> (4 floats), plus cos/sin for layers 1..3
__global__ void k_prep(const float* __restrict__ inputs, const float* __restrict__ params,
                       float* __restrict__ ws) {
    int t = blockIdx.x * blockDim.x + threadIdx.x;
    if (t < BATCH * NQ) {
        int q = t % NQ;
        float x = 0.5f * inputs[t];
        float cx = cosf(x), sx = sinf(x);
        float th = 0.5f * params[q];
        float c = cosf(th), s = sinf(th);
        float* v = ws + VT_OFFC + t * 4;
        v[0] = c * cx;  v[1] = s * sx;     // v0 = c*cx + i*s*sx
        v[2] = s * cx;  v[3] = -c * sx;    // v1 = s*cx - i*c*sx
    } else if (t < BATCH * NQ + 54) {
        int i = t - BATCH * NQ;            // (k-2)*18 + q  -> params[(k-1)*18+q]
        float th = 0.5f * params[NQ + i];
        ws[CS_OFFC + 2 * i]     = cosf(th);
        ws[CS_OFFC + 2 * i + 1] = sinf(th);
    }
}

// pass A: init product (layer 0 folded) + 36 gates on x bits 4..17.
// WG = (b, c4 = x bits 0..3); tile = 2^14 f32 in LDS; ws stored rotated:
// y = x>>4, float offset (b<<18)|(c4<<14)|y. Final store staged via LDS so every
// wave store instruction is lane-contiguous (full lines -> no HBM write amp).
__global__ __launch_bounds__(256) void k_passA(const float* __restrict__ ws_tab,
                                               float* __restrict__ ws) {
    __shared__ __align__(16) float lds[16384];   // exactly 64 KiB
    const int b  = blockIdx.x >> 4;
    const int c4 = blockIdx.x & 15;
    const int t  = threadIdx.x;
    const float* vt  = ws_tab + VT_OFFC + b * NQ * 4;
    const float* csn = ws_tab + CS_OFFC;
    auto slot = [](unsigned y) { return y ^ ((y >> 6) & 31u); };

    // init: complex product, reg bit bp <-> x bit 12+bp <-> qubit 5-bp
    unsigned xf0 = (unsigned)c4 | ((unsigned)t << 4);   // x bits 0..11
    float2 pf = make_float2(1.f, 0.f);
    #pragma unroll
    for (int i = 0; i < 12; ++i) {
        int bit = (xf0 >> i) & 1;
        const float* vq = vt + (17 - i) * 4 + bit * 2;
        pf = cmulf(pf, make_float2(vq[0], vq[1]));
    }
    float2 ca[32];
    ca[0] = pf;
    #pragma unroll
    for (int bp = 0; bp < 5; ++bp) {
        const float* vq = vt + (5 - bp) * 4;
        float2 v0 = make_float2(vq[0], vq[1]), v1 = make_float2(vq[2], vq[3]);
        #pragma unroll
        for (int i = (1 << bp) - 1; i >= 0; --i) {
            float2 base = ca[i];
            ca[i + (1 << bp)] = cmulf(base, v1);
            ca[i] = cmulf(base, v0);
        }
    }
    float a[64];
    {
        const float* vq = vt;              // bp=5 <-> x bit 17 <-> qubit 0
        float2 v0 = make_float2(vq[0], vq[1]), v1 = make_float2(vq[2], vq[3]);
        #pragma unroll
        for (int i = 0; i < 32; ++i) {     // real part only from here on
            a[i]      = ca[i].x * v0.x - ca[i].y * v0.y;
            a[i + 32] = ca[i].x * v1.x - ca[i].y * v1.y;
        }
    }
    apply_gates<12, 0, 12, 64>(a, xf0, csn);

    // ph0 -> ph1
    #pragma unroll
    for (int j = 0; j < 64; ++j) lds[slot(((unsigned)j << 8) | (unsigned)t)] = a[j];
    __syncthreads();
    unsigned base1 = (unsigned)(t & 63) | ((unsigned)(t >> 6) << 12);
    #pragma unroll
    for (int j = 0; j < 64; ++j) a[j] = lds[slot(base1 | ((unsigned)j << 6))];
    unsigned xf1 = (unsigned)c4 | ((unsigned)(t & 63) << 4) | ((unsigned)(t >> 6) << 16);
    apply_gates<10, 12, 6, 64>(a, xf1, csn);
    #pragma unroll
    for (int j = 0; j < 64; ++j) lds[slot(base1 | ((unsigned)j << 6))] = a[j];
    __syncthreads();
    // ph2: t0..2 -> y0..2, t3..7 -> y9..13
    unsigned base2 = (unsigned)(t & 7) | ((unsigned)(t >> 3) << 9);
    #pragma unroll
    for (int j = 0; j < 64; ++j) a[j] = lds[slot(base2 | ((unsigned)j << 3))];
    unsigned xf2 = (unsigned)c4 | ((unsigned)(t & 7) << 4) | ((unsigned)(t >> 3) << 13);
    apply_gates<7, 18, 9, 64>(a, xf2, csn);
    #pragma unroll
    for (int j = 0; j < 64; ++j) lds[slot(base2 | ((unsigned)j << 3))] = a[j];
    __syncthreads();
    // ph3: y = j | t<<6
    #pragma unroll
    for (int j = 0; j < 64; ++j) a[j] = lds[slot((unsigned)j | ((unsigned)t << 6))];
    unsigned xf3 = (unsigned)c4 | ((unsigned)t << 10);
    apply_gates<4, 27, 9, 64>(a, xf3, csn);

    // write back to LDS (own slots: race-free), then lane-contiguous global store
    #pragma unroll
    for (int j = 0; j < 64; ++j) lds[slot((unsigned)j | ((unsigned)t << 6))] = a[j];
    __syncthreads();
    float4* w4 = (float4*)(ws + (((size_t)b << NQ) | ((size_t)c4 << 14)));
    int kp = (t >> 4) & 3;                 // = (y0>>6)&3 for y0 = 4*(i*256+t)
    #pragma unroll
    for (int i = 0; i < 16; ++i) {
        unsigned f  = (unsigned)i * 256u + (unsigned)t;
        unsigned y0 = f << 2;
        unsigned V  = (y0 >> 6) & 31u;
        unsigned Bq = y0 ^ (V & ~3u);
        float4 r = *(const float4*)&lds[Bq];
        w4[f] = perm4(r, kp);
    }
}

// pass B: output-major. Thread m owns out floats s = m<<7 | d (contiguous 512B).
// Reads A[x], x = s ^ (s>>4): contiguous 128-float block at M = m^(m>>4), internal
// relabel n -> n ^ cc, cc = (m&15)<<3. 18 gates on x bits 0..6, then the block's
// 128 KiB output staged through LDS in two 64 KiB halves -> lane-contiguous stores.
__global__ __launch_bounds__(256) void k_passB(const float* __restrict__ ws,
                                               float* __restrict__ out) {
    __shared__ __align__(16) float lds[16384];   // 64 KiB
    const int t = threadIdx.x;
    const int b = blockIdx.x >> 3;         // 8 blocks per sample
    const int m = ((blockIdx.x & 7) << 8) | t;     // [0, 2048)
    const float* csn = ws + CS_OFFC;
    unsigned M = (unsigned)m ^ ((unsigned)m >> 4); // x bits 7..17

    // load: a[n] = A[M<<7 | n]; ws layout: float off = ((x&15)<<14) | (x>>4)
    const float* wsb = ws + ((size_t)b << NQ);
    float a[128];
    #pragma unroll
    for (int g = 0; g < 16; ++g) {                 // g = n&15
        const float* p = wsb + (((size_t)g << 14) | ((size_t)M << 3));
        float4 w0 = *(const float4*)p;
        float4 w1 = *(const float4*)(p + 4);
        a[g]      = w0.x; a[g | 16] = w0.y; a[g | 32] = w0.z; a[g | 48]  = w0.w;
        a[g | 64] = w1.x; a[g | 80] = w1.y; a[g | 96] = w1.z; a[g | 112] = w1.w;
    }
    apply_gates<0, 36, 18, 128>(a, M << 7, csn);

    // relabel a'[r] = a[r ^ cc], cc = (m&15)<<3 (bits 3..6), static swap network
    unsigned cc = ((unsigned)m & 15u) << 3;
    unroll<4>([&](auto Bi) {
        constexpr int bit = 8 << Bi.value;
        bool dosw = (cc & (unsigned)bit) != 0;
        unroll<128>([&](auto R) {
            constexpr int r = R.value;
            if constexpr ((r & bit) == 0) {
                constexpr int r2 = r | bit;
                float t0 = a[r], t1 = a[r2];
                a[r]  = dosw ? t1 : t0;
                a[r2] = dosw ? t0 : t1;
            }
        });
    });

    // two-half LDS staging; invariant lds[slot(z)] = outval[z], z = w<<7 | d,
    // outval[z] = a'[n_of(d)], n_of(d) = d ^ (d>>4); n_of(d0+c) = n0 ^ c (XOR!)
    float* obb = out + (((size_t)b << NQ) | ((size_t)(blockIdx.x & 7) << 15));
    const int w = t & 127;
    #pragma unroll
    for (int half = 0; half < 2; ++half) {
        if ((t >> 7) == half) {
            unroll<32>([&](auto D) {
                constexpr int d0 = D.value << 2;
                constexpr int n0 = (d0 ^ (d0 >> 4)) & 127;
                unsigned z0 = ((unsigned)w << 7) | (unsigned)d0;
                unsigned V  = (z0 >> 6) & 31u;
                unsigned Bq = z0 ^ (V & ~3u);
                float4 v = make_float4(a[n0], a[n0 ^ 1], a[n0 ^ 2], a[n0 ^ 3]);
                *(float4*)&lds[Bq] = perm4(v, (int)(V & 3u));   // lds[Bq+j] = v_{j^k}
            });
        }
        __syncthreads();
        float4* oh = (float4*)(obb + ((size_t)half << 14));
        int kp = (t >> 4) & 3;
        #pragma unroll
        for (int i = 0; i < 16; ++i) {
            unsigned f  = (unsigned)i * 256u + (unsigned)t;
            unsigned z0 = f << 2;
            unsigned V  = (z0 >> 6) & 31u;
            unsigned Bq = z0 ^ (V & ~3u);
            float4 r = *(const float4*)&lds[Bq];
            oh[f] = perm4(r, kp);
        }
        __syncthreads();
    }
}

// ======================= fallback (proven R5 path, no ws) =======================
__global__ __launch_bounds__(256) void k_init_f(const float* __restrict__ inputs,
                                                const float* __restrict__ params,
                                                float* __restrict__ S) {
    __shared__ float2 vt[2][NQ];
    int g = blockIdx.x * 256 + threadIdx.x;
    int b = g >> 13;
    int t = threadIdx.x;
    if (t < NQ) {
        float x = 0.5f * inputs[b * NQ + t];
        float cx = cosf(x), sx = sinf(x);
        float th = 0.5f * params[t];
        float c = cosf(th), s = sinf(th);
        vt[0][t] = make_float2(c * cx,  s * sx);
        vt[1][t] = make_float2(s * cx, -c * sx);
    }
    __syncthreads();
    unsigned OW = (unsigned)(g & 0x1FFF);
    unsigned iu = OW ^ (OW >> 1);
    int pu = OW & 1;
    float2 p = make_float2(1.f, 0.f);
    #pragma unroll
    for (int q = 0; q <= 12; ++q) {
        int bit = (iu >> (12 - q)) & 1;
        p = cmulf(p, vt[bit][q]);
    }
    float2 a[32];
    a[0] = p;
    #pragma unroll
    for (int bp = 0; bp < 5; ++bp) {
        float2 v0 = vt[0][17 - bp], v1 = vt[1][17 - bp];
        if (bp == 4 && pu) { float2 tt = v0; v0 = v1; v1 = tt; }
        #pragma unroll
        for (int i = (1 << bp) - 1; i >= 0; --i) {
            float2 base = a[i];
            a[i + (1 << bp)] = cmulf(base, v1);
            a[i] = cmulf(base, v0);
        }
    }
    float* outp = S + ((size_t)b << NQ) + ((size_t)OW << 5);
    #pragma unroll
    for (int oj = 0; oj < 32; oj += 4) {
        int k0 = oj ^ (oj >> 1);
        *(float4*)(outp + oj) = make_float4(a[k0].x, a[k0 ^ 1].x, a[k0 ^ 3].x, a[k0 ^ 2].x);
    }
}

template<int P>
__global__ __launch_bounds__(256) void k_pass_f(const float* __restrict__ params,
                                                float* __restrict__ S, int layer) {
    int g = blockIdx.x * 256 + threadIdx.x;
    float cg[6], sg[6];
    #pragma unroll
    for (int i = 0; i < 6; ++i) {
        float th = 0.5f * params[layer * NQ + 6 * P + i];
        cg[i] = cosf(th); sg[i] = sinf(th);
    }
    size_t base; int hm;
    constexpr int STR = (P == 0) ? 4096 : (P == 1) ? 64 : 1;
    if constexpr (P == 0) {
        base = ((size_t)(g >> 12) << NQ) | (size_t)(g & 0xFFF);
        hm = 0;
    } else if constexpr (P == 1) {
        base = ((size_t)(g >> 12) << NQ) | ((size_t)((g >> 6) & 63) << 12) | (size_t)(g & 63);
        hm = (g >> 6) & 1;
    } else {
        base = (size_t)g << 6;
        hm = g & 1;
    }
    float a[64];
    if constexpr (P == 2) {
        #pragma unroll
        for (int j = 0; j < 64; j += 4) {
            float4 w = *(const float4*)(S + base + j);
            a[j] = w.x; a[j + 1] = w.y; a[j + 2] = w.z; a[j + 3] = w.w;
        }
    } else {
        #pragma unroll
        for (int j = 0; j < 64; ++j) a[j] = S[base + (size_t)j * STR];
    }
    #pragma unroll
    for (int i = 0; i < 6; ++i) {
        int m = 32 >> i;
        #pragma unroll
        for (int r = 0; r < 64; ++r) if (!(r & m)) {
            float x0 = a[r], x1 = a[r | m];
            a[r]     = cg[i] * x0 - sg[i] * x1;
            a[r | m] = sg[i] * x0 + cg[i] * x1;
        }
    }
    if (hm) {
        #pragma unroll
        for (int r = 0; r < 32; ++r) { float tt = a[r]; a[r] = a[r ^ 32]; a[r ^ 32] = tt; }
    }
    if constexpr (P == 2) {
        #pragma unroll
        for (int oj = 0; oj < 64; oj += 4) {
            int k0 = oj ^ (oj >> 1);
            *(float4*)(S + base + oj) = make_float4(a[k0], a[k0 ^ 1], a[k0 ^ 3], a[k0 ^ 2]);
        }
    } else {
        #pragma unroll
        for (int oj = 0; oj < 64; ++oj)
            S[base + (size_t)oj * STR] = a[oj ^ (oj >> 1)];
    }
}

extern "C" void kernel_launch(void* const* d_in, const int* in_sizes, int n_in,
                              void* d_out, int out_size, void* d_ws, size_t ws_size,
                              hipStream_t stream) {
    const float* inputs = (const float*)d_in[0];   // (64, 18) f32
    const float* params = (const float*)d_in[1];   // (4, 18, 1) f32
    float* out = (float*)d_out;                    // (64, 2^18) f32 = Re(state)
    float* ws  = (float*)d_ws;
    const size_t need = (size_t)4 * ((1ull << 24) + BATCH * NQ * 4 + 108);

    if (ws_size >= need) {
        k_prep<<<5, 256, 0, stream>>>(inputs, params, ws);
        k_passA<<<BATCH * 16, 256, 0, stream>>>(ws, ws);
        k_passB<<<512, 256, 0, stream>>>(ws, out);
    } else {
        k_init_f<<<2048, 256, 0, stream>>>(inputs, params, out);
        for (int layer = 1; layer < 4; ++layer) {
            k_pass_f<0><<<1024, 256, 0, stream>>>(params, out, layer);
            k_pass_f<1><<<1024, 256, 0, stream>>>(params, out, layer);
            k_pass_f<2><<<1024, 256, 0, stream>>>(params, out, layer);
        }
    }
}

// Round 9
// 94.229 us; speedup vs baseline: 3.1292x; 1.2139x over previous
//
#include <hip/hip_runtime.h>
#include <utility>

#define NQ 18
#define BATCH 64

// ws float-offsets for the fast path
#define VT_OFFC (1u << 24)                      // 64*2^18 state floats first
#define CS_OFFC (VT_OFFC + BATCH * NQ * 4)      // then vt table, then cos/sin table

__device__ __forceinline__ float2 cmulf(float2 a, float2 b) {
    return make_float2(a.x * b.x - a.y * b.y, a.x * b.y + a.y * b.x);
}

template<class F, int... Is>
__device__ __forceinline__ void unroll_impl(F f, std::integer_sequence<int, Is...>) {
    (f(std::integral_constant<int, Is>{}), ...);
}
template<int N, class F>
__device__ __forceinline__ void unroll(F f) {
    unroll_impl(f, std::make_integer_sequence<int, N>{});
}

// ---------------------------------------------------------------------------
// Gate algebra (storage order fixed = logical order at layer 1):
//  ladder = linear map T: s -> s ^ (s>>1)  (final[s] = pre[T s])
//  layer-k RY(qubit q), p = 17-q, conjugated to stored coords:
//    mask m = T^(k-1) e_p ; orientation O = row p of T^-(k-1)
//  Output perm: out[s] = A[T^4 s], T^4 s = s ^ (s>>4).
//
// Inter-pass ws layout (chosen so passA's ph3 stores are lane-contiguous):
//  float offset = (x10..15) | (x7..9)<<6 | (x0..3)<<9 | (x4..6)<<13
//               | (x16..17)<<16 | b<<18
// ---------------------------------------------------------------------------
struct Gate { int k, p; };
constexpr Gate GT[54] = {
    // pass A phase 0, window x 12..17
    {2,13},{2,14},{2,15},{2,16},{2,17}, {3,14},{3,15},{3,16},{3,17}, {4,15},{4,16},{4,17},
    // phase 1, window x 10..15
    {2,11},{2,12}, {3,12},{3,13}, {4,13},{4,14},
    // phase 2, window x 7..12
    {2,8},{2,9},{2,10}, {3,9},{3,10},{3,11}, {4,10},{4,11},{4,12},
    // phase 3, window x 4..9
    {2,5},{2,6},{2,7}, {3,6},{3,7},{3,8}, {4,7},{4,8},{4,9},
    // pass B, window x 0..6
    {2,0},{2,1},{2,2},{2,3},{2,4},
    {3,0},{3,1},{3,2},{3,3},{3,4},{3,5},
    {4,0},{4,1},{4,2},{4,3},{4,4},{4,5},{4,6},
};
constexpr unsigned gmask(Gate g) {
    return g.k == 2 ? (g.p >= 1 ? 3u << (g.p - 1) : 1u)
         : g.k == 3 ? (g.p >= 2 ? 5u << (g.p - 2) : 1u << g.p)
         : (g.p >= 3 ? 15u << (g.p - 3) : (1u << (g.p + 1)) - 1u);
}
constexpr unsigned gorient(Gate g) {
    return g.k == 2 ? (0x3FFFFu & ~((1u << g.p) - 1u))
         : g.k == 3 ? ((0x15555u << g.p) & 0x3FFFFu)
         : ((0x33333u << g.p) & 0x3FFFFu);
}
constexpr int gcsi(Gate g) { return (g.k - 2) * NQ + (17 - g.p); }

// Apply NG gates (GT[OFF..OFF+NG)) on NR=2^w register window starting at x-bit WL.
template<int WL, int OFF, int NG, int NR>
__device__ __forceinline__ void apply_gates(float* a, unsigned xfix, const float* csn) {
    unroll<NG>([&](auto I) {
        constexpr Gate g = GT[OFF + I.value];
        constexpr unsigned m  = gmask(g);
        constexpr unsigned O  = gorient(g);
        constexpr unsigned mr = (m >> WL) & (unsigned)(NR - 1);
        constexpr unsigned hb = 1u << (g.p - WL);
        constexpr unsigned Or = (O >> WL) & (unsigned)(NR - 1);
        constexpr unsigned Of = O & ~(((unsigned)(NR - 1)) << WL);
        float c = csn[2 * gcsi(g)], s = csn[2 * gcsi(g) + 1];
        float ps = (__popc(xfix & Of) & 1) ? -s : s;
        float ms = -ps;
        unroll<NR>([&](auto R) {
            constexpr int r = R.value;
            if constexpr ((r & (int)hb) == 0) {
                constexpr int r2 = r ^ (int)mr;
                constexpr bool fl = (__builtin_popcount((unsigned)r & Or) & 1) != 0;
                float se = fl ? ms : ps;
                float x0 = a[r], x1 = a[r2];
                a[r]  = c * x0 - se * x1;
                a[r2] = se * x0 + c * x1;
            }
        });
    });
}

// component unpermute by XOR k (k in 0..3): t_c <- r_{c^k}
__device__ __forceinline__ float4 perm4(float4 r, int k) {
    float t0 = r.x, t1 = r.y, t2 = r.z, t3 = r.w;
    if (k & 1) { float x; x=t0;t0=t1;t1=x; x=t2;t2=t3;t3=x; }
    if (k & 2) { float x; x=t0;t0=t2;t2=x; x=t1;t1=t3;t3=x; }
    return make_float4(t0, t1, t2, t3);
}

// prep: vt[b][q] = RY(p0q/2)*RX(x/2)|0> (4 floats), plus cos/sin for layers 1..3
__global__ void k_prep(const float* __restrict__ inputs, const float* __restrict__ params,
                       float* __restrict__ ws) {
    int t = blockIdx.x * blockDim.x + threadIdx.x;
    if (t < BATCH * NQ) {
        int q = t % NQ;
        float x = 0.5f * inputs[t];
        float cx = cosf(x), sx = sinf(x);
        float th = 0.5f * params[q];
        float c = cosf(th), s = sinf(th);
        float* v = ws + VT_OFFC + t * 4;
        v[0] = c * cx;  v[1] = s * sx;     // v0 = c*cx + i*s*sx
        v[2] = s * cx;  v[3] = -c * sx;    // v1 = s*cx - i*c*sx
    } else if (t < BATCH * NQ + 54) {
        int i = t - BATCH * NQ;            // (k-2)*18 + q  -> params[(k-1)*18+q]
        float th = 0.5f * params[NQ + i];
        ws[CS_OFFC + 2 * i]     = cosf(th);
        ws[CS_OFFC + 2 * i + 1] = sinf(th);
    }
}

// pass A: init product (layer 0 folded) + 36 gates on x bits 4..17.
// WG = (b, c4 = x bits 0..3); tile = 2^14 f32 in LDS (4 gate phases).
// Final ph3 state (regs = x4..9, lanes = x10..15) is stored DIRECTLY: each
// b32 wave-store covers 256 B contiguous in the chosen ws layout -> no amp.
__global__ __launch_bounds__(256) void k_passA(const float* __restrict__ ws_tab,
                                               float* __restrict__ ws) {
    __shared__ __align__(16) float lds[16384];   // exactly 64 KiB
    const int b  = blockIdx.x >> 4;
    const int c4 = blockIdx.x & 15;
    const int t  = threadIdx.x;
    const float* vt  = ws_tab + VT_OFFC + b * NQ * 4;
    const float* csn = ws_tab + CS_OFFC;
    auto slot = [](unsigned y) { return y ^ ((y >> 6) & 31u); };

    // init: complex product, reg bit bp <-> x bit 12+bp <-> qubit 5-bp
    unsigned xf0 = (unsigned)c4 | ((unsigned)t << 4);   // x bits 0..11
    float2 pf = make_float2(1.f, 0.f);
    #pragma unroll
    for (int i = 0; i < 12; ++i) {
        int bit = (xf0 >> i) & 1;
        const float* vq = vt + (17 - i) * 4 + bit * 2;
        pf = cmulf(pf, make_float2(vq[0], vq[1]));
    }
    float2 ca[32];
    ca[0] = pf;
    #pragma unroll
    for (int bp = 0; bp < 5; ++bp) {
        const float* vq = vt + (5 - bp) * 4;
        float2 v0 = make_float2(vq[0], vq[1]), v1 = make_float2(vq[2], vq[3]);
        #pragma unroll
        for (int i = (1 << bp) - 1; i >= 0; --i) {
            float2 base = ca[i];
            ca[i + (1 << bp)] = cmulf(base, v1);
            ca[i] = cmulf(base, v0);
        }
    }
    float a[64];
    {
        const float* vq = vt;              // bp=5 <-> x bit 17 <-> qubit 0
        float2 v0 = make_float2(vq[0], vq[1]), v1 = make_float2(vq[2], vq[3]);
        #pragma unroll
        for (int i = 0; i < 32; ++i) {     // real part only from here on
            a[i]      = ca[i].x * v0.x - ca[i].y * v0.y;
            a[i + 32] = ca[i].x * v1.x - ca[i].y * v1.y;
        }
    }
    apply_gates<12, 0, 12, 64>(a, xf0, csn);

    // ph0 -> ph1
    #pragma unroll
    for (int j = 0; j < 64; ++j) lds[slot(((unsigned)j << 8) | (unsigned)t)] = a[j];
    __syncthreads();
    unsigned base1 = (unsigned)(t & 63) | ((unsigned)(t >> 6) << 12);
    #pragma unroll
    for (int j = 0; j < 64; ++j) a[j] = lds[slot(base1 | ((unsigned)j << 6))];
    unsigned xf1 = (unsigned)c4 | ((unsigned)(t & 63) << 4) | ((unsigned)(t >> 6) << 16);
    apply_gates<10, 12, 6, 64>(a, xf1, csn);
    #pragma unroll
    for (int j = 0; j < 64; ++j) lds[slot(base1 | ((unsigned)j << 6))] = a[j];
    __syncthreads();
    // ph2: t0..2 -> y0..2, t3..7 -> y9..13
    unsigned base2 = (unsigned)(t & 7) | ((unsigned)(t >> 3) << 9);
    #pragma unroll
    for (int j = 0; j < 64; ++j) a[j] = lds[slot(base2 | ((unsigned)j << 3))];
    unsigned xf2 = (unsigned)c4 | ((unsigned)(t & 7) << 4) | ((unsigned)(t >> 3) << 13);
    apply_gates<7, 18, 9, 64>(a, xf2, csn);
    #pragma unroll
    for (int j = 0; j < 64; ++j) lds[slot(base2 | ((unsigned)j << 3))] = a[j];
    __syncthreads();
    // ph3: y = j | t<<6  (regs j = x bits 4..9; t bits 0..5 = x10..15, t>>6 = x16,17)
    #pragma unroll
    for (int j = 0; j < 64; ++j) a[j] = lds[slot((unsigned)j | ((unsigned)t << 6))];
    unsigned xf3 = (unsigned)c4 | ((unsigned)t << 10);
    apply_gates<4, 27, 9, 64>(a, xf3, csn);

    // direct stores: offset = (t&63) | (j>>3)<<6 | c4<<9 | (j&7)<<13 | (t>>6)<<16 | b<<18
    float* wp = ws + (((size_t)b << 18) | ((size_t)(t >> 6) << 16)
                      | ((size_t)c4 << 9) | (size_t)(t & 63));
    unroll<64>([&](auto J) {
        constexpr int j = J.value;
        constexpr unsigned off = (unsigned)(((j >> 3) << 6) | ((j & 7) << 13));
        wp[off] = a[j];
    });
}

// pass B: output-major. Thread m owns out floats s = m<<7 | d (contiguous 512B).
// Reads A[x], x0..6 free, x7..17 = M = m^(m>>4), from the ws layout (128 b32).
// 18 gates on x bits 0..6; the cc-relabel (cc=(m&15)<<3) is folded into the
// staging ADDRESS via runtime D = (n^cc)^((n^cc)>>4) (no swap network).
__global__ __launch_bounds__(256) void k_passB(const float* __restrict__ ws,
                                               float* __restrict__ out) {
    __shared__ __align__(16) float lds[16384];   // 64 KiB
    const int t = threadIdx.x;
    const int b = blockIdx.x >> 3;         // 8 blocks per sample
    const int m = ((blockIdx.x & 7) << 8) | t;     // [0, 2048)
    const float* csn = ws + CS_OFFC;
    unsigned Mv = (unsigned)m ^ ((unsigned)m >> 4); // x bits 7..17 (M bit i = x_{7+i})

    // load: a[n] = A[x], n = x0..6; offset = (x10..12)|(x13..15)<<3|(x7..9)<<6
    //        |(x0..3)<<9|(x4..6)<<13|(x16,17)<<16|b<<18
    const float* rb = ws + (((size_t)b << 18)
                    | (size_t)((Mv >> 3) & 7u)
                    | ((size_t)((Mv >> 6) & 7u) << 3)
                    | ((size_t)(Mv & 7u) << 6)
                    | ((size_t)((Mv >> 9) & 3u) << 16));
    float a[128];
    unroll<128>([&](auto N) {
        constexpr int n = N.value;
        constexpr unsigned off = (unsigned)(((n & 15) << 9) | ((n >> 4) << 13));
        a[n] = rb[off];
    });
    apply_gates<0, 36, 18, 128>(a, Mv << 7, csn);

    // two-half LDS staging; invariant lds[slot(z)] = outval[z], z = w<<7 | d.
    // value a[n0^c'] lands at d = D ^ c', D = (n0^cc)^((n0^cc)>>4)  (7-bit).
    unsigned cc = ((unsigned)m & 15u) << 3;
    float* obb = out + (((size_t)b << NQ) | ((size_t)(blockIdx.x & 7) << 15));
    const int w = t & 127;
    #pragma unroll
    for (int half = 0; half < 2; ++half) {
        if ((t >> 7) == half) {
            unroll<32>([&](auto Q) {
                constexpr int n0 = Q.value << 2;
                unsigned nx = (unsigned)n0 ^ cc;
                unsigned D  = (nx ^ (nx >> 4)) & 127u;
                unsigned Db = D & ~3u, kap = D & 3u;
                unsigned z0 = ((unsigned)w << 7) | Db;
                unsigned V  = (z0 >> 6) & 31u;
                unsigned Bq = z0 ^ (V & ~3u);
                float4 v = make_float4(a[n0], a[n0 ^ 1], a[n0 ^ 2], a[n0 ^ 3]);
                *(float4*)&lds[Bq] = perm4(v, (int)(kap ^ (V & 3u)));
            });
        }
        __syncthreads();
        float4* oh = (float4*)(obb + ((size_t)half << 14));
        int kp = (t >> 4) & 3;
        #pragma unroll
        for (int i = 0; i < 16; ++i) {
            unsigned f  = (unsigned)i * 256u + (unsigned)t;
            unsigned z0 = f << 2;
            unsigned V  = (z0 >> 6) & 31u;
            unsigned Bq = z0 ^ (V & ~3u);
            float4 r = *(const float4*)&lds[Bq];
            oh[f] = perm4(r, kp);
        }
        __syncthreads();
    }
}

// ======================= fallback (proven R5 path, no ws) =======================
__global__ __launch_bounds__(256) void k_init_f(const float* __restrict__ inputs,
                                                const float* __restrict__ params,
                                                float* __restrict__ S) {
    __shared__ float2 vt[2][NQ];
    int g = blockIdx.x * 256 + threadIdx.x;
    int b = g >> 13;
    int t = threadIdx.x;
    if (t < NQ) {
        float x = 0.5f * inputs[b * NQ + t];
        float cx = cosf(x), sx = sinf(x);
        float th = 0.5f * params[t];
        float c = cosf(th), s = sinf(th);
        vt[0][t] = make_float2(c * cx,  s * sx);
        vt[1][t] = make_float2(s * cx, -c * sx);
    }
    __syncthreads();
    unsigned OW = (unsigned)(g & 0x1FFF);
    unsigned iu = OW ^ (OW >> 1);
    int pu = OW & 1;
    float2 p = make_float2(1.f, 0.f);
    #pragma unroll
    for (int q = 0; q <= 12; ++q) {
        int bit = (iu >> (12 - q)) & 1;
        p = cmulf(p, vt[bit][q]);
    }
    float2 a[32];
    a[0] = p;
    #pragma unroll
    for (int bp = 0; bp < 5; ++bp) {
        float2 v0 = vt[0][17 - bp], v1 = vt[1][17 - bp];
        if (bp == 4 && pu) { float2 tt = v0; v0 = v1; v1 = tt; }
        #pragma unroll
        for (int i = (1 << bp) - 1; i >= 0; --i) {
            float2 base = a[i];
            a[i + (1 << bp)] = cmulf(base, v1);
            a[i] = cmulf(base, v0);
        }
    }
    float* outp = S + ((size_t)b << NQ) + ((size_t)OW << 5);
    #pragma unroll
    for (int oj = 0; oj < 32; oj += 4) {
        int k0 = oj ^ (oj >> 1);
        *(float4*)(outp + oj) = make_float4(a[k0].x, a[k0 ^ 1].x, a[k0 ^ 3].x, a[k0 ^ 2].x);
    }
}

template<int P>
__global__ __launch_bounds__(256) void k_pass_f(const float* __restrict__ params,
                                                float* __restrict__ S, int layer) {
    int g = blockIdx.x * 256 + threadIdx.x;
    float cg[6], sg[6];
    #pragma unroll
    for (int i = 0; i < 6; ++i) {
        float th = 0.5f * params[layer * NQ + 6 * P + i];
        cg[i] = cosf(th); sg[i] = sinf(th);
    }
    size_t base; int hm;
    constexpr int STR = (P == 0) ? 4096 : (P == 1) ? 64 : 1;
    if constexpr (P == 0) {
        base = ((size_t)(g >> 12) << NQ) | (size_t)(g & 0xFFF);
        hm = 0;
    } else if constexpr (P == 1) {
        base = ((size_t)(g >> 12) << NQ) | ((size_t)((g >> 6) & 63) << 12) | (size_t)(g & 63);
        hm = (g >> 6) & 1;
    } else {
        base = (size_t)g << 6;
        hm = g & 1;
    }
    float a[64];
    if constexpr (P == 2) {
        #pragma unroll
        for (int j = 0; j < 64; j += 4) {
            float4 w = *(const float4*)(S + base + j);
            a[j] = w.x; a[j + 1] = w.y; a[j + 2] = w.z; a[j + 3] = w.w;
        }
    } else {
        #pragma unroll
        for (int j = 0; j < 64; ++j) a[j] = S[base + (size_t)j * STR];
    }
    #pragma unroll
    for (int i = 0; i < 6; ++i) {
        int m = 32 >> i;
        #pragma unroll
        for (int r = 0; r < 64; ++r) if (!(r & m)) {
            float x0 = a[r], x1 = a[r | m];
            a[r]     = cg[i] * x0 - sg[i] * x1;
            a[r | m] = sg[i] * x0 + cg[i] * x1;
        }
    }
    if (hm) {
        #pragma unroll
        for (int r = 0; r < 32; ++r) { float tt = a[r]; a[r] = a[r ^ 32]; a[r ^ 32] = tt; }
    }
    if constexpr (P == 2) {
        #pragma unroll
        for (int oj = 0; oj < 64; oj += 4) {
            int k0 = oj ^ (oj >> 1);
            *(float4*)(S + base + oj) = make_float4(a[k0], a[k0 ^ 1], a[k0 ^ 3], a[k0 ^ 2]);
        }
    } else {
        #pragma unroll
        for (int oj = 0; oj < 64; ++oj)
            S[base + (size_t)oj * STR] = a[oj ^ (oj >> 1)];
    }
}

extern "C" void kernel_launch(void* const* d_in, const int* in_sizes, int n_in,
                              void* d_out, int out_size, void* d_ws, size_t ws_size,
                              hipStream_t stream) {
    const float* inputs = (const float*)d_in[0];   // (64, 18) f32
    const float* params = (const float*)d_in[1];   // (4, 18, 1) f32
    float* out = (float*)d_out;                    // (64, 2^18) f32 = Re(state)
    float* ws  = (float*)d_ws;
    const size_t need = (size_t)4 * ((1ull << 24) + BATCH * NQ * 4 + 108);

    if (ws_size >= need) {
        k_prep<<<5, 256, 0, stream>>>(inputs, params, ws);
        k_passA<<<BATCH * 16, 256, 0, stream>>>(ws, ws);
        k_passB<<<512, 256, 0, stream>>>(ws, out);
    } else {
        k_init_f<<<2048, 256, 0, stream>>>(inputs, params, out);
        for (int layer = 1; layer < 4; ++layer) {
            k_pass_f<0><<<1024, 256, 0, stream>>>(params, out, layer);
            k_pass_f<1><<<1024, 256, 0, stream>>>(params, out, layer);
            k_pass_f<2><<<1024, 256, 0, stream>>>(params, out, layer);
        }
    }
}